// Round 8
// baseline (593.212 us; speedup 1.0000x reference)
//
#include <hip/hip_runtime.h>

#define BB 4
#define LL 4096
#define DD 128

typedef float f32x4 __attribute__((ext_vector_type(4)));
typedef short bf16x8 __attribute__((ext_vector_type(8)));
typedef unsigned short u16x8 __attribute__((ext_vector_type(8)));
typedef unsigned short u16x4 __attribute__((ext_vector_type(4)));
typedef int i32x4 __attribute__((ext_vector_type(4)));

__device__ __forceinline__ unsigned short f2bf(float f) {
  union { float f; unsigned u; } v; v.f = f;
  unsigned r = v.u + 0x7FFFu + ((v.u >> 16) & 1u);
  return (unsigned short)(r >> 16);
}

// ---- fused: row norms (fp32-exact) + bf16 conversion of Q,K ----
__global__ __launch_bounds__(256) void kNC(const float* __restrict__ Q,
                                           const float* __restrict__ K,
                                           unsigned short* __restrict__ Qb,
                                           unsigned short* __restrict__ Kb,
                                           float* __restrict__ qn,
                                           float* __restrict__ kn) {
  int tid = threadIdx.x;
  int row = blockIdx.x * 16 + (tid >> 4);  // 0..32767
  int part = tid & 15;
  const float* src; unsigned short* dst; float* nd; int r;
  if (row < BB * LL) { src = Q; dst = Qb; nd = qn; r = row; }
  else { src = K; dst = Kb; nd = kn; r = row - BB * LL; }
  const float* p = src + (size_t)r * DD + part * 8;
  f32x4 a = *(const f32x4*)p, b = *(const f32x4*)(p + 4);
  float s = a.x * a.x + a.y * a.y + a.z * a.z + a.w * a.w +
            b.x * b.x + b.y * b.y + b.z * b.z + b.w * b.w;
  s += __shfl_xor(s, 1); s += __shfl_xor(s, 2);
  s += __shfl_xor(s, 4); s += __shfl_xor(s, 8);
  u16x8 h;
  h[0] = f2bf(a.x); h[1] = f2bf(a.y); h[2] = f2bf(a.z); h[3] = f2bf(a.w);
  h[4] = f2bf(b.x); h[5] = f2bf(b.y); h[6] = f2bf(b.z); h[7] = f2bf(b.w);
  *(u16x8*)(dst + (size_t)r * DD + part * 8) = h;
  if (part == 0) nd[r] = s;
}

// ---- V transpose to bf16: VT[b][d][k] = bf16(V[b][k][d]) ----
__global__ __launch_bounds__(256) void kVT(const float* __restrict__ V,
                                           unsigned short* __restrict__ VT) {
  __shared__ unsigned short t[128][68];
  int bx = blockIdx.x;
  int kt = bx & 63, b = bx >> 6;
  int k0 = kt * 64;
  int tid = threadIdx.x;
  const float* Vb = V + ((size_t)b * LL + k0) * DD;
  #pragma unroll
  for (int i = 0; i < 8; ++i) {
    int flat = tid + i * 256;
    int row = flat >> 5, c4 = flat & 31;
    f32x4 v = *(const f32x4*)(Vb + row * DD + c4 * 4);
    #pragma unroll
    for (int j = 0; j < 4; ++j) t[c4 * 4 + j][row] = f2bf(v[j]);
  }
  __syncthreads();
  unsigned short* Ob = VT + (size_t)b * DD * LL + k0;
  #pragma unroll
  for (int i = 0; i < 8; ++i) {
    int flat = tid + i * 256;
    int d = flat >> 4, c = flat & 15;
    *(u16x4*)(Ob + (size_t)d * LL + c * 4) = *(const u16x4*)&t[d][c * 4];
  }
}

// ---- kernel A8: direct C-frag stores, no LDS, lean registers, (256,3) ----
// grid 1024: qb(64) x b(4) x ks(4). Wave w owns q rows [qb*64+w*16,+16) over
// k in [ks*1024,+1024). Swapped MFMA (A=K,B=Q): lane(lr,lc) holds S for
// q=lc-row, k=m*16+lr*4+r -> f32x4 stores cover 64B/row x 16 rows per instr.
// Per-lane state: qf[4]=16v, mask dbuf=32v, scalar l_acc -> fits 3 waves/SIMD.
__global__ __launch_bounds__(256, 3) void kA8(
    const unsigned short* __restrict__ Qb, const unsigned short* __restrict__ Kb,
    const int* __restrict__ mask, const float* __restrict__ qn,
    const float* __restrict__ kn, float* __restrict__ scores,
    float* __restrict__ dist2, float* __restrict__ l_part) {
  int bx = blockIdx.x;
  int qb = bx & 63, b = (bx >> 6) & 3, ks = bx >> 8;
  int tid = threadIdx.x;
  int w = tid >> 6, lane = tid & 63, lr = lane >> 4, lc = lane & 15;
  int qg = qb * 64 + w * 16;
  size_t bL = (size_t)b * LL;

  bf16x8 qf[4];
  {
    const unsigned short* qp = Qb + (bL + qg + lc) * DD;
    #pragma unroll
    for (int c = 0; c < 4; ++c)
      qf[c] = *(const bf16x8*)(qp + c * 32 + lr * 8);
  }
  float qn_l = qn[bL + qg + lc];
  size_t rowoff = (bL + qg + lc) * (size_t)LL;  // this lane's q-row
  float l_acc = 0.f;

  auto LOADM = [&](i32x4 (&mr)[4], int t) {
    int k0 = ks * 1024 + t * 64;
    #pragma unroll
    for (int m = 0; m < 4; ++m)
      mr[m] = *(const i32x4*)(mask + rowoff + k0 + m * 16 + lr * 4);
  };

  auto TILE = [&](i32x4 (&mr)[4], int t) {
    int k0 = ks * 1024 + t * 64;
    #pragma unroll
    for (int m = 0; m < 4; ++m) {
      int kk = k0 + m * 16;
      const unsigned short* kp = Kb + (bL + kk + lc) * DD;
      f32x4 S = (f32x4){0.f, 0.f, 0.f, 0.f};
      #pragma unroll
      for (int c = 0; c < 4; ++c) {
        bf16x8 af = *(const bf16x8*)(kp + c * 32 + lr * 8);
        S = __builtin_amdgcn_mfma_f32_16x16x32_bf16(af, qf[c], S, 0, 0, 0);
      }
      f32x4 kn4 = *(const f32x4*)(kn + bL + kk + lr * 4);
      f32x4 d2, sv;
      float le = 0.f;
      #pragma unroll
      for (int r = 0; r < 4; ++r) {
        float d = qn_l + kn4[r] - 2.0f * S[r];
        d2[r] = d;
        float sc = d * (-1.0f / 256.0f);
        bool ms = (mr[m][r] == 0);
        sv[r] = ms ? -__builtin_inff() : sc;
        le += ms ? 0.f : __expf(sc);
      }
      size_t off = rowoff + kk + lr * 4;
      *(f32x4*)(dist2 + off) = d2;
      *(f32x4*)(scores + off) = sv;
      l_acc += le;
    }
  };

  i32x4 mA[4], mB[4];
  LOADM(mA, 0);
  #pragma unroll
  for (int tt = 0; tt < 8; ++tt) {
    LOADM(mB, 2 * tt + 1);
    TILE(mA, 2 * tt);
    LOADM(mA, (tt < 7) ? (2 * tt + 2) : 0);  // tail dup is harmless
    TILE(mB, 2 * tt + 1);
  }

  // reduce over lr (lane bits 4,5); lane<16 holds row qg+lane
  float v = l_acc;
  v += __shfl_xor(v, 16);
  v += __shfl_xor(v, 32);
  if (lane < 16)
    l_part[(size_t)ks * (BB * LL) + bL + qg + lane] = v;
}

// ---- kernel B5: double-buffered, reg-prefetched, 1 barrier/iter ----
__global__ __launch_bounds__(256, 2) void kB5(
    const float* __restrict__ scores, const float* __restrict__ l_part,
    const unsigned short* __restrict__ VT, float* __restrict__ attn,
    float* __restrict__ O_part) {
  __shared__ short p_lds[2][64][72];
  __shared__ short v_lds[2][128][72];
  __shared__ float rl_lds[64];
  int bx = blockIdx.x;
  int qb = bx & 63, b = (bx >> 6) & 3, ks = bx >> 8;
  int tid = threadIdx.x;
  int wq = tid >> 6, l = tid & 63, lr = l >> 4, lc = l & 15;
  int q0 = qb * 64;
  int k_base = ks * 1024;

  if (tid < 64) {
    float s = 0.f;
    #pragma unroll
    for (int sp = 0; sp < 4; ++sp)
      s += l_part[(size_t)sp * (BB * LL) + (size_t)b * LL + q0 + tid];
    rl_lds[tid] = 1.0f / s;
  }

  const float* Sb = scores + (size_t)b * LL * LL + (size_t)q0 * LL;
  float* Ab = attn + (size_t)b * LL * LL + (size_t)q0 * LL;
  const unsigned short* Vb = VT + (size_t)b * DD * LL;

  int srow[4], sc4[4];
  #pragma unroll
  for (int i = 0; i < 4; ++i) {
    int flat = tid + i * 256;
    srow[i] = flat >> 4; sc4[i] = flat & 15;
  }
  int vd[8], vc[8];
  #pragma unroll
  for (int i = 0; i < 8; ++i) {
    int flat = tid + i * 256;
    vd[i] = flat >> 4; vc[i] = flat & 15;
  }

  f32x4 rS[4];
  u16x4 rV[8];
  auto LOADT = [&](int t) {
    int k0 = k_base + t * 64;
    #pragma unroll
    for (int i = 0; i < 4; ++i)
      rS[i] = __builtin_nontemporal_load(
          (const f32x4*)(Sb + (size_t)srow[i] * LL + k0 + sc4[i] * 4));
    #pragma unroll
    for (int i = 0; i < 8; ++i)
      rV[i] = *(const u16x4*)(Vb + (size_t)vd[i] * LL + k0 + vc[i] * 4);
  };

  auto PROCESS = [&](int t, int buf) {
    int k0 = k_base + t * 64;
    #pragma unroll
    for (int i = 0; i < 4; ++i) {
      float r = rl_lds[srow[i]];
      f32x4 s4 = rS[i];
      f32x4 p4;
      p4.x = __expf(s4.x) * r; p4.y = __expf(s4.y) * r;
      p4.z = __expf(s4.z) * r; p4.w = __expf(s4.w) * r;
      *(f32x4*)(Ab + (size_t)srow[i] * LL + k0 + sc4[i] * 4) = p4;
      u16x4 h;
      h[0] = f2bf(p4.x); h[1] = f2bf(p4.y); h[2] = f2bf(p4.z); h[3] = f2bf(p4.w);
      *(u16x4*)&p_lds[buf][srow[i]][sc4[i] * 4] = h;
    }
    #pragma unroll
    for (int i = 0; i < 8; ++i)
      *(u16x4*)&v_lds[buf][vd[i]][vc[i] * 4] = rV[i];
  };

  f32x4 o[8];
  #pragma unroll
  for (int f = 0; f < 8; ++f) o[f] = (f32x4){0.f, 0.f, 0.f, 0.f};

  LOADT(0);
  __syncthreads();          // rl_lds ready
  PROCESS(0, 0);
  LOADT(1);
  __syncthreads();          // buf0 ready

  for (int t = 0; t < 16; ++t) {
    int cur = t & 1;
    bf16x8 pa[2];
    #pragma unroll
    for (int c = 0; c < 2; ++c)
      pa[c] = *(bf16x8*)&p_lds[cur][wq * 16 + lc][c * 32 + lr * 8];
    #pragma unroll
    for (int f = 0; f < 8; ++f) {
      #pragma unroll
      for (int c = 0; c < 2; ++c) {
        bf16x8 vb = *(bf16x8*)&v_lds[cur][f * 16 + lc][c * 32 + lr * 8];
        o[f] = __builtin_amdgcn_mfma_f32_16x16x32_bf16(pa[c], vb, o[f], 0, 0, 0);
      }
    }
    if (t < 15) {
      PROCESS(t + 1, cur ^ 1);
      if (t < 14) LOADT(t + 2);
    }
    __syncthreads();
  }

  float* Ob = O_part + (size_t)ks * ((size_t)BB * LL * DD);
  #pragma unroll
  for (int f = 0; f < 8; ++f) {
    #pragma unroll
    for (int r = 0; r < 4; ++r) {
      int row = q0 + wq * 16 + lr * 4 + r;
      Ob[((size_t)b * LL + row) * DD + f * 16 + lc] = o[f][r];
    }
  }
}

// ---- reduce the four O partials into out ----
__global__ __launch_bounds__(256) void kR(const float* __restrict__ O_part,
                                          float* __restrict__ out) {
  size_t idx = (size_t)blockIdx.x * 256 + threadIdx.x;
  const size_t N4 = (size_t)BB * LL * DD / 4;
  const f32x4* a = (const f32x4*)O_part;
  f32x4 v = (a[idx] + a[idx + N4]) + (a[idx + 2 * N4] + a[idx + 3 * N4]);
  ((f32x4*)out)[idx] = v;
}

extern "C" void kernel_launch(void* const* d_in, const int* in_sizes, int n_in,
                              void* d_out, int out_size, void* d_ws, size_t ws_size,
                              hipStream_t stream) {
  const float* Q = (const float*)d_in[0];
  const float* K = (const float*)d_in[1];
  const float* V = (const float*)d_in[2];
  const int* mask = (const int*)d_in[3];

  float* out = (float*)d_out;                        // [4,4096,128]
  float* attn = out + (size_t)BB * LL * DD;          // [4,4096,4096]
  float* scores = attn + (size_t)BB * LL * LL;       // [4,4096,4096]
  float* dist2 = scores + (size_t)BB * LL * LL;      // [4,4096,4096]

  float* qn = (float*)d_ws;                                   // 16384 f
  float* kn = qn + BB * LL;                                   // 16384 f
  float* l_part = kn + BB * LL;                               // 4*16384 f
  unsigned short* Qbf = (unsigned short*)(l_part + 4 * BB * LL);   // 4 MB
  unsigned short* Kbf = Qbf + (size_t)BB * LL * DD;                // 4 MB
  unsigned short* VTb = Kbf + (size_t)BB * LL * DD;                // 4 MB
  float* O_part = (float*)(VTb + (size_t)BB * LL * DD);            // 4 x 8 MB

  hipLaunchKernelGGL(kNC, dim3(2048), dim3(256), 0, stream, Q, K, Qbf, Kbf, qn, kn);
  hipLaunchKernelGGL(kVT, dim3(256), dim3(256), 0, stream, V, VTb);
  hipLaunchKernelGGL(kA8, dim3(1024), dim3(256), 0, stream, Qbf, Kbf, mask, qn,
                     kn, scores, dist2, l_part);
  hipLaunchKernelGGL(kB5, dim3(1024), dim3(256), 0, stream, scores, l_part, VTb,
                     attn, O_part);
  hipLaunchKernelGGL(kR, dim3(2048), dim3(256), 0, stream, O_part, out);
}

// Round 9
// 510.164 us; speedup vs baseline: 1.1628x; 1.1628x over previous
//
#include <hip/hip_runtime.h>

#define BB 4
#define LL 4096
#define DD 128

typedef float f32x4 __attribute__((ext_vector_type(4)));
typedef short bf16x8 __attribute__((ext_vector_type(8)));
typedef unsigned short u16x8 __attribute__((ext_vector_type(8)));
typedef unsigned short u16x4 __attribute__((ext_vector_type(4)));
typedef int i32x4 __attribute__((ext_vector_type(4)));

__device__ __forceinline__ unsigned short f2bf(float f) {
  union { float f; unsigned u; } v; v.f = f;
  unsigned r = v.u + 0x7FFFu + ((v.u >> 16) & 1u);
  return (unsigned short)(r >> 16);
}

// ---- fused: row norms (fp32-exact) + bf16 conversion of Q,K ----
__global__ __launch_bounds__(256) void kNC(const float* __restrict__ Q,
                                           const float* __restrict__ K,
                                           unsigned short* __restrict__ Qb,
                                           unsigned short* __restrict__ Kb,
                                           float* __restrict__ qn,
                                           float* __restrict__ kn) {
  int tid = threadIdx.x;
  int row = blockIdx.x * 16 + (tid >> 4);  // 0..32767
  int part = tid & 15;
  const float* src; unsigned short* dst; float* nd; int r;
  if (row < BB * LL) { src = Q; dst = Qb; nd = qn; r = row; }
  else { src = K; dst = Kb; nd = kn; r = row - BB * LL; }
  const float* p = src + (size_t)r * DD + part * 8;
  f32x4 a = *(const f32x4*)p, b = *(const f32x4*)(p + 4);
  float s = a.x * a.x + a.y * a.y + a.z * a.z + a.w * a.w +
            b.x * b.x + b.y * b.y + b.z * b.z + b.w * b.w;
  s += __shfl_xor(s, 1); s += __shfl_xor(s, 2);
  s += __shfl_xor(s, 4); s += __shfl_xor(s, 8);
  u16x8 h;
  h[0] = f2bf(a.x); h[1] = f2bf(a.y); h[2] = f2bf(a.z); h[3] = f2bf(a.w);
  h[4] = f2bf(b.x); h[5] = f2bf(b.y); h[6] = f2bf(b.z); h[7] = f2bf(b.w);
  *(u16x8*)(dst + (size_t)r * DD + part * 8) = h;
  if (part == 0) nd[r] = s;
}

// ---- V transpose to bf16: VT[b][d][k] = bf16(V[b][k][d]) ----
__global__ __launch_bounds__(256) void kVT(const float* __restrict__ V,
                                           unsigned short* __restrict__ VT) {
  __shared__ unsigned short t[128][68];
  int bx = blockIdx.x;
  int kt = bx & 63, b = bx >> 6;
  int k0 = kt * 64;
  int tid = threadIdx.x;
  const float* Vb = V + ((size_t)b * LL + k0) * DD;
  #pragma unroll
  for (int i = 0; i < 8; ++i) {
    int flat = tid + i * 256;
    int row = flat >> 5, c4 = flat & 31;
    f32x4 v = *(const f32x4*)(Vb + row * DD + c4 * 4);
    #pragma unroll
    for (int j = 0; j < 4; ++j) t[c4 * 4 + j][row] = f2bf(v[j]);
  }
  __syncthreads();
  unsigned short* Ob = VT + (size_t)b * DD * LL + k0;
  #pragma unroll
  for (int i = 0; i < 8; ++i) {
    int flat = tid + i * 256;
    int d = flat >> 4, c = flat & 15;
    *(u16x4*)(Ob + (size_t)d * LL + c * 4) = *(const u16x4*)&t[d][c * 4];
  }
}

// ---- kernel A9: direct C-frag stores, (256,2) [no spill], 2-deep mask
// prefetch via 4 rotating named buffers. grid 1024: qb(64) x b(4) x ks(4).
// Wave w owns q rows [qb*64+w*16,+16) over k in [ks*1024,+1024).
// Swapped MFMA (A=K,B=Q): lane(lr,lc) holds S for q-row lc, k=m*16+lr*4+r;
// direct f32x4 stores cover 64B contiguous x 16 rows per instruction.
__global__ __launch_bounds__(256, 2) void kA9(
    const unsigned short* __restrict__ Qb, const unsigned short* __restrict__ Kb,
    const int* __restrict__ mask, const float* __restrict__ qn,
    const float* __restrict__ kn, float* __restrict__ scores,
    float* __restrict__ dist2, float* __restrict__ l_part) {
  int bx = blockIdx.x;
  int qb = bx & 63, b = (bx >> 6) & 3, ks = bx >> 8;
  int tid = threadIdx.x;
  int w = tid >> 6, lane = tid & 63, lr = lane >> 4, lc = lane & 15;
  int qg = qb * 64 + w * 16;
  size_t bL = (size_t)b * LL;

  bf16x8 qf[4];
  {
    const unsigned short* qp = Qb + (bL + qg + lc) * DD;
    #pragma unroll
    for (int c = 0; c < 4; ++c)
      qf[c] = *(const bf16x8*)(qp + c * 32 + lr * 8);
  }
  float qn_l = qn[bL + qg + lc];
  size_t rowoff = (bL + qg + lc) * (size_t)LL;  // this lane's q-row
  float l_acc = 0.f;

  auto LOADM = [&](i32x4 (&mr)[4], int t) {
    int tc = (t <= 15) ? t : 0;  // tail dup is harmless
    int k0 = ks * 1024 + tc * 64;
    #pragma unroll
    for (int m = 0; m < 4; ++m)
      mr[m] = *(const i32x4*)(mask + rowoff + k0 + m * 16 + lr * 4);
  };

  auto TILE = [&](i32x4 (&mr)[4], int t) {
    int k0 = ks * 1024 + t * 64;
    #pragma unroll
    for (int m = 0; m < 4; ++m) {
      int kk = k0 + m * 16;
      const unsigned short* kp = Kb + (bL + kk + lc) * DD;
      f32x4 S = (f32x4){0.f, 0.f, 0.f, 0.f};
      #pragma unroll
      for (int c = 0; c < 4; ++c) {
        bf16x8 af = *(const bf16x8*)(kp + c * 32 + lr * 8);
        S = __builtin_amdgcn_mfma_f32_16x16x32_bf16(af, qf[c], S, 0, 0, 0);
      }
      f32x4 kn4 = *(const f32x4*)(kn + bL + kk + lr * 4);
      f32x4 d2, sv;
      float le = 0.f;
      #pragma unroll
      for (int r = 0; r < 4; ++r) {
        float d = qn_l + kn4[r] - 2.0f * S[r];
        d2[r] = d;
        float sc = d * (-1.0f / 256.0f);
        bool ms = (mr[m][r] == 0);
        sv[r] = ms ? -__builtin_inff() : sc;
        le += ms ? 0.f : __expf(sc);
      }
      size_t off = rowoff + kk + lr * 4;
      *(f32x4*)(dist2 + off) = d2;
      *(f32x4*)(scores + off) = sv;
      l_acc += le;
    }
  };

  // 2-deep mask pipeline: 4 named buffers, 4 tiles per macro-iter.
  i32x4 m0[4], m1[4], m2[4], m3[4];
  LOADM(m0, 0);
  LOADM(m1, 1);
  #pragma unroll
  for (int j = 0; j < 4; ++j) {
    LOADM(m2, 4 * j + 2);
    TILE(m0, 4 * j);
    LOADM(m3, 4 * j + 3);
    TILE(m1, 4 * j + 1);
    LOADM(m0, 4 * j + 4);
    TILE(m2, 4 * j + 2);
    LOADM(m1, 4 * j + 5);
    TILE(m3, 4 * j + 3);
  }

  // reduce over lr (lane bits 4,5); lane<16 holds row qg+lane
  float v = l_acc;
  v += __shfl_xor(v, 16);
  v += __shfl_xor(v, 32);
  if (lane < 16)
    l_part[(size_t)ks * (BB * LL) + bL + qg + lane] = v;
}

// ---- kernel B5: double-buffered, reg-prefetched, 1 barrier/iter ----
__global__ __launch_bounds__(256, 2) void kB5(
    const float* __restrict__ scores, const float* __restrict__ l_part,
    const unsigned short* __restrict__ VT, float* __restrict__ attn,
    float* __restrict__ O_part) {
  __shared__ short p_lds[2][64][72];
  __shared__ short v_lds[2][128][72];
  __shared__ float rl_lds[64];
  int bx = blockIdx.x;
  int qb = bx & 63, b = (bx >> 6) & 3, ks = bx >> 8;
  int tid = threadIdx.x;
  int wq = tid >> 6, l = tid & 63, lr = l >> 4, lc = l & 15;
  int q0 = qb * 64;
  int k_base = ks * 1024;

  if (tid < 64) {
    float s = 0.f;
    #pragma unroll
    for (int sp = 0; sp < 4; ++sp)
      s += l_part[(size_t)sp * (BB * LL) + (size_t)b * LL + q0 + tid];
    rl_lds[tid] = 1.0f / s;
  }

  const float* Sb = scores + (size_t)b * LL * LL + (size_t)q0 * LL;
  float* Ab = attn + (size_t)b * LL * LL + (size_t)q0 * LL;
  const unsigned short* Vb = VT + (size_t)b * DD * LL;

  int srow[4], sc4[4];
  #pragma unroll
  for (int i = 0; i < 4; ++i) {
    int flat = tid + i * 256;
    srow[i] = flat >> 4; sc4[i] = flat & 15;
  }
  int vd[8], vc[8];
  #pragma unroll
  for (int i = 0; i < 8; ++i) {
    int flat = tid + i * 256;
    vd[i] = flat >> 4; vc[i] = flat & 15;
  }

  f32x4 rS[4];
  u16x4 rV[8];
  auto LOADT = [&](int t) {
    int k0 = k_base + t * 64;
    #pragma unroll
    for (int i = 0; i < 4; ++i)
      rS[i] = __builtin_nontemporal_load(
          (const f32x4*)(Sb + (size_t)srow[i] * LL + k0 + sc4[i] * 4));
    #pragma unroll
    for (int i = 0; i < 8; ++i)
      rV[i] = *(const u16x4*)(Vb + (size_t)vd[i] * LL + k0 + vc[i] * 4);
  };

  auto PROCESS = [&](int t, int buf) {
    int k0 = k_base + t * 64;
    #pragma unroll
    for (int i = 0; i < 4; ++i) {
      float r = rl_lds[srow[i]];
      f32x4 s4 = rS[i];
      f32x4 p4;
      p4.x = __expf(s4.x) * r; p4.y = __expf(s4.y) * r;
      p4.z = __expf(s4.z) * r; p4.w = __expf(s4.w) * r;
      *(f32x4*)(Ab + (size_t)srow[i] * LL + k0 + sc4[i] * 4) = p4;
      u16x4 h;
      h[0] = f2bf(p4.x); h[1] = f2bf(p4.y); h[2] = f2bf(p4.z); h[3] = f2bf(p4.w);
      *(u16x4*)&p_lds[buf][srow[i]][sc4[i] * 4] = h;
    }
    #pragma unroll
    for (int i = 0; i < 8; ++i)
      *(u16x4*)&v_lds[buf][vd[i]][vc[i] * 4] = rV[i];
  };

  f32x4 o[8];
  #pragma unroll
  for (int f = 0; f < 8; ++f) o[f] = (f32x4){0.f, 0.f, 0.f, 0.f};

  LOADT(0);
  __syncthreads();          // rl_lds ready
  PROCESS(0, 0);
  LOADT(1);
  __syncthreads();          // buf0 ready

  for (int t = 0; t < 16; ++t) {
    int cur = t & 1;
    bf16x8 pa[2];
    #pragma unroll
    for (int c = 0; c < 2; ++c)
      pa[c] = *(bf16x8*)&p_lds[cur][wq * 16 + lc][c * 32 + lr * 8];
    #pragma unroll
    for (int f = 0; f < 8; ++f) {
      #pragma unroll
      for (int c = 0; c < 2; ++c) {
        bf16x8 vb = *(bf16x8*)&v_lds[cur][f * 16 + lc][c * 32 + lr * 8];
        o[f] = __builtin_amdgcn_mfma_f32_16x16x32_bf16(pa[c], vb, o[f], 0, 0, 0);
      }
    }
    if (t < 15) {
      PROCESS(t + 1, cur ^ 1);
      if (t < 14) LOADT(t + 2);
    }
    __syncthreads();
  }

  float* Ob = O_part + (size_t)ks * ((size_t)BB * LL * DD);
  #pragma unroll
  for (int f = 0; f < 8; ++f) {
    #pragma unroll
    for (int r = 0; r < 4; ++r) {
      int row = q0 + wq * 16 + lr * 4 + r;
      Ob[((size_t)b * LL + row) * DD + f * 16 + lc] = o[f][r];
    }
  }
}

// ---- reduce the four O partials into out ----
__global__ __launch_bounds__(256) void kR(const float* __restrict__ O_part,
                                          float* __restrict__ out) {
  size_t idx = (size_t)blockIdx.x * 256 + threadIdx.x;
  const size_t N4 = (size_t)BB * LL * DD / 4;
  const f32x4* a = (const f32x4*)O_part;
  f32x4 v = (a[idx] + a[idx + N4]) + (a[idx + 2 * N4] + a[idx + 3 * N4]);
  ((f32x4*)out)[idx] = v;
}

extern "C" void kernel_launch(void* const* d_in, const int* in_sizes, int n_in,
                              void* d_out, int out_size, void* d_ws, size_t ws_size,
                              hipStream_t stream) {
  const float* Q = (const float*)d_in[0];
  const float* K = (const float*)d_in[1];
  const float* V = (const float*)d_in[2];
  const int* mask = (const int*)d_in[3];

  float* out = (float*)d_out;                        // [4,4096,128]
  float* attn = out + (size_t)BB * LL * DD;          // [4,4096,4096]
  float* scores = attn + (size_t)BB * LL * LL;       // [4,4096,4096]
  float* dist2 = scores + (size_t)BB * LL * LL;      // [4,4096,4096]

  float* qn = (float*)d_ws;                                   // 16384 f
  float* kn = qn + BB * LL;                                   // 16384 f
  float* l_part = kn + BB * LL;                               // 4*16384 f
  unsigned short* Qbf = (unsigned short*)(l_part + 4 * BB * LL);   // 4 MB
  unsigned short* Kbf = Qbf + (size_t)BB * LL * DD;                // 4 MB
  unsigned short* VTb = Kbf + (size_t)BB * LL * DD;                // 4 MB
  float* O_part = (float*)(VTb + (size_t)BB * LL * DD);            // 4 x 8 MB

  hipLaunchKernelGGL(kNC, dim3(2048), dim3(256), 0, stream, Q, K, Qbf, Kbf, qn, kn);
  hipLaunchKernelGGL(kVT, dim3(256), dim3(256), 0, stream, V, VTb);
  hipLaunchKernelGGL(kA9, dim3(1024), dim3(256), 0, stream, Qbf, Kbf, mask, qn,
                     kn, scores, dist2, l_part);
  hipLaunchKernelGGL(kB5, dim3(1024), dim3(256), 0, stream, scores, l_part, VTb,
                     attn, O_part);
  hipLaunchKernelGGL(kR, dim3(2048), dim3(256), 0, stream, O_part, out);
}

// Round 10
// 486.889 us; speedup vs baseline: 1.2184x; 1.0478x over previous
//
#include <hip/hip_runtime.h>

#define BB 4
#define LL 4096
#define DD 128

typedef float f32x4 __attribute__((ext_vector_type(4)));
typedef short bf16x8 __attribute__((ext_vector_type(8)));
typedef unsigned short u16x8 __attribute__((ext_vector_type(8)));
typedef unsigned short u16x4 __attribute__((ext_vector_type(4)));
typedef int i32x4 __attribute__((ext_vector_type(4)));

__device__ __forceinline__ unsigned short f2bf(float f) {
  union { float f; unsigned u; } v; v.f = f;
  unsigned r = v.u + 0x7FFFu + ((v.u >> 16) & 1u);
  return (unsigned short)(r >> 16);
}

// ---- fused: row norms (fp32-exact) + bf16 conversion of Q,K ----
__global__ __launch_bounds__(256) void kNC(const float* __restrict__ Q,
                                           const float* __restrict__ K,
                                           unsigned short* __restrict__ Qb,
                                           unsigned short* __restrict__ Kb,
                                           float* __restrict__ qn,
                                           float* __restrict__ kn) {
  int tid = threadIdx.x;
  int row = blockIdx.x * 16 + (tid >> 4);  // 0..32767
  int part = tid & 15;
  const float* src; unsigned short* dst; float* nd; int r;
  if (row < BB * LL) { src = Q; dst = Qb; nd = qn; r = row; }
  else { src = K; dst = Kb; nd = kn; r = row - BB * LL; }
  const float* p = src + (size_t)r * DD + part * 8;
  f32x4 a = *(const f32x4*)p, b = *(const f32x4*)(p + 4);
  float s = a.x * a.x + a.y * a.y + a.z * a.z + a.w * a.w +
            b.x * b.x + b.y * b.y + b.z * b.z + b.w * b.w;
  s += __shfl_xor(s, 1); s += __shfl_xor(s, 2);
  s += __shfl_xor(s, 4); s += __shfl_xor(s, 8);
  u16x8 h;
  h[0] = f2bf(a.x); h[1] = f2bf(a.y); h[2] = f2bf(a.z); h[3] = f2bf(a.w);
  h[4] = f2bf(b.x); h[5] = f2bf(b.y); h[6] = f2bf(b.z); h[7] = f2bf(b.w);
  *(u16x8*)(dst + (size_t)r * DD + part * 8) = h;
  if (part == 0) nd[r] = s;
}

// ---- V transpose to bf16: VT[b][d][k] = bf16(V[b][k][d]) ----
__global__ __launch_bounds__(256) void kVT(const float* __restrict__ V,
                                           unsigned short* __restrict__ VT) {
  __shared__ unsigned short t[128][68];
  int bx = blockIdx.x;
  int kt = bx & 63, b = bx >> 6;
  int k0 = kt * 64;
  int tid = threadIdx.x;
  const float* Vb = V + ((size_t)b * LL + k0) * DD;
  #pragma unroll
  for (int i = 0; i < 8; ++i) {
    int flat = tid + i * 256;
    int row = flat >> 5, c4 = flat & 31;
    f32x4 v = *(const f32x4*)(Vb + row * DD + c4 * 4);
    #pragma unroll
    for (int j = 0; j < 4; ++j) t[c4 * 4 + j][row] = f2bf(v[j]);
  }
  __syncthreads();
  unsigned short* Ob = VT + (size_t)b * DD * LL + k0;
  #pragma unroll
  for (int i = 0; i < 8; ++i) {
    int flat = tid + i * 256;
    int d = flat >> 4, c = flat & 15;
    *(u16x4*)(Ob + (size_t)d * LL + c * 4) = *(const u16x4*)&t[d][c * 4];
  }
}

// ---- kernel A11: kA4 store layout + software pipeline ----
// grid 1024: qb(64) x b(4) x ks(4), (256,2). Wave w owns q rows
// [qb*64+w*16,+16) over k in [ks*1024,+1024). Per tile: ISSUE (K-frag loads +
// 16 MFMA -> S in regs), SPILL (ds_write to double-buffered slds), STORE
// (ds_read transposed + exp + 4rows x 256B global stores). Schedule
// ISSUE(t+1) -> STORE(t) -> SPILL(t+1) so t+1's vmem/MFMA latency hides
// under t's store phase. l_acc lane-local, reduced once at end.
__global__ __launch_bounds__(256, 2) void kA11(
    const unsigned short* __restrict__ Qb, const unsigned short* __restrict__ Kb,
    const int* __restrict__ mask, const float* __restrict__ qn,
    const float* __restrict__ kn, float* __restrict__ scores,
    float* __restrict__ dist2, float* __restrict__ l_part) {
  __shared__ float slds[2][4][16][64];  // [buf][wave][q][k-chunk], XOR-swizzled
  int bx = blockIdx.x;
  int qb = bx & 63, b = (bx >> 6) & 3, ks = bx >> 8;
  int tid = threadIdx.x;
  int w = tid >> 6, lane = tid & 63, lr = lane >> 4, lc = lane & 15;
  int qg = qb * 64 + w * 16;
  size_t bL = (size_t)b * LL;

  bf16x8 qf[4];
  {
    const unsigned short* qp = Qb + (bL + qg + lc) * DD;
    #pragma unroll
    for (int c = 0; c < 4; ++c)
      qf[c] = *(const bf16x8*)(qp + c * 32 + lr * 8);
  }

  float qn_s[4];
  size_t rowoff[4];
  #pragma unroll
  for (int s = 0; s < 4; ++s) {
    qn_s[s] = qn[bL + qg + s * 4 + lr];
    rowoff[s] = (bL + qg + s * 4 + lr) * (size_t)LL;
  }
  float l_acc[4] = {0.f, 0.f, 0.f, 0.f};

  auto ISSUE = [&](int t, f32x4 (&Sr)[4]) {
    int k0 = ks * 1024 + t * 64;
    #pragma unroll
    for (int m = 0; m < 4; ++m) {
      const unsigned short* kp = Kb + (bL + k0 + m * 16 + lc) * DD;
      f32x4 S = (f32x4){0.f, 0.f, 0.f, 0.f};
      #pragma unroll
      for (int c = 0; c < 4; ++c) {
        bf16x8 af = *(const bf16x8*)(kp + c * 32 + lr * 8);
        S = __builtin_amdgcn_mfma_f32_16x16x32_bf16(af, qf[c], S, 0, 0, 0);
      }
      Sr[m] = S;
    }
  };

  auto SPILL = [&](f32x4 (&Sr)[4], int buf) {
    #pragma unroll
    for (int m = 0; m < 4; ++m) {
      int swz = ((m * 4 + lr) ^ lc) & 15;
      *(f32x4*)&slds[buf][w][lc][swz * 4] = Sr[m];
    }
  };

  auto LOADM = [&](i32x4 (&mr)[4], int t) {
    int tc = (t <= 15) ? t : 0;  // tail dup is harmless
    int k0 = ks * 1024 + tc * 64;
    #pragma unroll
    for (int s = 0; s < 4; ++s)
      mr[s] = *(const i32x4*)(mask + rowoff[s] + k0 + lc * 4);
  };

  auto STORE = [&](i32x4 (&mr)[4], int t, int buf) {
    int k0 = ks * 1024 + t * 64;
    f32x4 kn4 = *(const f32x4*)(kn + bL + k0 + lc * 4);
    #pragma unroll
    for (int s = 0; s < 4; ++s) {
      int row = s * 4 + lr;
      int swz = (lc ^ row) & 15;
      f32x4 S = *(const f32x4*)&slds[buf][w][row][swz * 4];
      f32x4 d2, sv;
      float le = 0.f;
      #pragma unroll
      for (int r = 0; r < 4; ++r) {
        float d = qn_s[s] + kn4[r] - 2.0f * S[r];
        d2[r] = d;
        float sc = d * (-1.0f / 256.0f);
        bool ms = (mr[s][r] == 0);
        sv[r] = ms ? -__builtin_inff() : sc;
        le += ms ? 0.f : __expf(sc);
      }
      size_t off = rowoff[s] + k0 + lc * 4;
      *(f32x4*)(dist2 + off) = d2;
      *(f32x4*)(scores + off) = sv;
      l_acc[s] += le;  // lane-local; reduced once at kernel end
    }
  };

  i32x4 mA[4], mB[4];
  f32x4 Sa[4], Sb2[4];
  LOADM(mA, 0);
  LOADM(mB, 1);
  ISSUE(0, Sa);
  SPILL(Sa, 0);
  #pragma unroll
  for (int tt = 0; tt < 8; ++tt) {
    ISSUE(2 * tt + 1, Sb2);       // K-loads + MFMAs for t+1 in flight
    STORE(mA, 2 * tt, 0);         // store t under t+1's latency
    SPILL(Sb2, 1);
    LOADM(mA, 2 * tt + 2);
    if (tt < 7) ISSUE(2 * tt + 2, Sa);
    STORE(mB, 2 * tt + 1, 1);
    if (tt < 7) SPILL(Sa, 0);
    LOADM(mB, 2 * tt + 3);
  }

  // reduce each l_acc[s] over the 16 k-segments (lane bits 0..3)
  #pragma unroll
  for (int s = 0; s < 4; ++s) {
    float v = l_acc[s];
    v += __shfl_xor(v, 1); v += __shfl_xor(v, 2);
    v += __shfl_xor(v, 4); v += __shfl_xor(v, 8);
    if (lc == 0)
      l_part[(size_t)ks * (BB * LL) + bL + qg + s * 4 + lr] = v;
  }
}

// ---- kernel B5: double-buffered, reg-prefetched, 1 barrier/iter ----
__global__ __launch_bounds__(256, 2) void kB5(
    const float* __restrict__ scores, const float* __restrict__ l_part,
    const unsigned short* __restrict__ VT, float* __restrict__ attn,
    float* __restrict__ O_part) {
  __shared__ short p_lds[2][64][72];
  __shared__ short v_lds[2][128][72];
  __shared__ float rl_lds[64];
  int bx = blockIdx.x;
  int qb = bx & 63, b = (bx >> 6) & 3, ks = bx >> 8;
  int tid = threadIdx.x;
  int wq = tid >> 6, l = tid & 63, lr = l >> 4, lc = l & 15;
  int q0 = qb * 64;
  int k_base = ks * 1024;

  if (tid < 64) {
    float s = 0.f;
    #pragma unroll
    for (int sp = 0; sp < 4; ++sp)
      s += l_part[(size_t)sp * (BB * LL) + (size_t)b * LL + q0 + tid];
    rl_lds[tid] = 1.0f / s;
  }

  const float* Sb = scores + (size_t)b * LL * LL + (size_t)q0 * LL;
  float* Ab = attn + (size_t)b * LL * LL + (size_t)q0 * LL;
  const unsigned short* Vb = VT + (size_t)b * DD * LL;

  int srow[4], sc4[4];
  #pragma unroll
  for (int i = 0; i < 4; ++i) {
    int flat = tid + i * 256;
    srow[i] = flat >> 4; sc4[i] = flat & 15;
  }
  int vd[8], vc[8];
  #pragma unroll
  for (int i = 0; i < 8; ++i) {
    int flat = tid + i * 256;
    vd[i] = flat >> 4; vc[i] = flat & 15;
  }

  f32x4 rS[4];
  u16x4 rV[8];
  auto LOADT = [&](int t) {
    int k0 = k_base + t * 64;
    #pragma unroll
    for (int i = 0; i < 4; ++i)
      rS[i] = __builtin_nontemporal_load(
          (const f32x4*)(Sb + (size_t)srow[i] * LL + k0 + sc4[i] * 4));
    #pragma unroll
    for (int i = 0; i < 8; ++i)
      rV[i] = *(const u16x4*)(Vb + (size_t)vd[i] * LL + k0 + vc[i] * 4);
  };

  auto PROCESS = [&](int t, int buf) {
    int k0 = k_base + t * 64;
    #pragma unroll
    for (int i = 0; i < 4; ++i) {
      float r = rl_lds[srow[i]];
      f32x4 s4 = rS[i];
      f32x4 p4;
      p4.x = __expf(s4.x) * r; p4.y = __expf(s4.y) * r;
      p4.z = __expf(s4.z) * r; p4.w = __expf(s4.w) * r;
      *(f32x4*)(Ab + (size_t)srow[i] * LL + k0 + sc4[i] * 4) = p4;
      u16x4 h;
      h[0] = f2bf(p4.x); h[1] = f2bf(p4.y); h[2] = f2bf(p4.z); h[3] = f2bf(p4.w);
      *(u16x4*)&p_lds[buf][srow[i]][sc4[i] * 4] = h;
    }
    #pragma unroll
    for (int i = 0; i < 8; ++i)
      *(u16x4*)&v_lds[buf][vd[i]][vc[i] * 4] = rV[i];
  };

  f32x4 o[8];
  #pragma unroll
  for (int f = 0; f < 8; ++f) o[f] = (f32x4){0.f, 0.f, 0.f, 0.f};

  LOADT(0);
  __syncthreads();          // rl_lds ready
  PROCESS(0, 0);
  LOADT(1);
  __syncthreads();          // buf0 ready

  for (int t = 0; t < 16; ++t) {
    int cur = t & 1;
    bf16x8 pa[2];
    #pragma unroll
    for (int c = 0; c < 2; ++c)
      pa[c] = *(bf16x8*)&p_lds[cur][wq * 16 + lc][c * 32 + lr * 8];
    #pragma unroll
    for (int f = 0; f < 8; ++f) {
      #pragma unroll
      for (int c = 0; c < 2; ++c) {
        bf16x8 vb = *(bf16x8*)&v_lds[cur][f * 16 + lc][c * 32 + lr * 8];
        o[f] = __builtin_amdgcn_mfma_f32_16x16x32_bf16(pa[c], vb, o[f], 0, 0, 0);
      }
    }
    if (t < 15) {
      PROCESS(t + 1, cur ^ 1);
      if (t < 14) LOADT(t + 2);
    }
    __syncthreads();
  }

  float* Ob = O_part + (size_t)ks * ((size_t)BB * LL * DD);
  #pragma unroll
  for (int f = 0; f < 8; ++f) {
    #pragma unroll
    for (int r = 0; r < 4; ++r) {
      int row = q0 + wq * 16 + lr * 4 + r;
      Ob[((size_t)b * LL + row) * DD + f * 16 + lc] = o[f][r];
    }
  }
}

// ---- reduce the four O partials into out ----
__global__ __launch_bounds__(256) void kR(const float* __restrict__ O_part,
                                          float* __restrict__ out) {
  size_t idx = (size_t)blockIdx.x * 256 + threadIdx.x;
  const size_t N4 = (size_t)BB * LL * DD / 4;
  const f32x4* a = (const f32x4*)O_part;
  f32x4 v = (a[idx] + a[idx + N4]) + (a[idx + 2 * N4] + a[idx + 3 * N4]);
  ((f32x4*)out)[idx] = v;
}

extern "C" void kernel_launch(void* const* d_in, const int* in_sizes, int n_in,
                              void* d_out, int out_size, void* d_ws, size_t ws_size,
                              hipStream_t stream) {
  const float* Q = (const float*)d_in[0];
  const float* K = (const float*)d_in[1];
  const float* V = (const float*)d_in[2];
  const int* mask = (const int*)d_in[3];

  float* out = (float*)d_out;                        // [4,4096,128]
  float* attn = out + (size_t)BB * LL * DD;          // [4,4096,4096]
  float* scores = attn + (size_t)BB * LL * LL;       // [4,4096,4096]
  float* dist2 = scores + (size_t)BB * LL * LL;      // [4,4096,4096]

  float* qn = (float*)d_ws;                                   // 16384 f
  float* kn = qn + BB * LL;                                   // 16384 f
  float* l_part = kn + BB * LL;                               // 4*16384 f
  unsigned short* Qbf = (unsigned short*)(l_part + 4 * BB * LL);   // 4 MB
  unsigned short* Kbf = Qbf + (size_t)BB * LL * DD;                // 4 MB
  unsigned short* VTb = Kbf + (size_t)BB * LL * DD;                // 4 MB
  float* O_part = (float*)(VTb + (size_t)BB * LL * DD);            // 4 x 8 MB

  hipLaunchKernelGGL(kNC, dim3(2048), dim3(256), 0, stream, Q, K, Qbf, Kbf, qn, kn);
  hipLaunchKernelGGL(kVT, dim3(256), dim3(256), 0, stream, V, VTb);
  hipLaunchKernelGGL(kA11, dim3(1024), dim3(256), 0, stream, Qbf, Kbf, mask, qn,
                     kn, scores, dist2, l_part);
  hipLaunchKernelGGL(kB5, dim3(1024), dim3(256), 0, stream, scores, l_part, VTb,
                     attn, O_part);
  hipLaunchKernelGGL(kR, dim3(2048), dim3(256), 0, stream, O_part, out);
}

// Round 11
// 427.350 us; speedup vs baseline: 1.3881x; 1.1393x over previous
//
#include <hip/hip_runtime.h>

#define BB 4
#define LL 4096
#define DD 128

typedef float f32x4 __attribute__((ext_vector_type(4)));
typedef short bf16x8 __attribute__((ext_vector_type(8)));
typedef unsigned short u16x8 __attribute__((ext_vector_type(8)));
typedef unsigned short u16x4 __attribute__((ext_vector_type(4)));
typedef int i32x4 __attribute__((ext_vector_type(4)));

__device__ __forceinline__ unsigned short f2bf(float f) {
  union { float f; unsigned u; } v; v.f = f;
  unsigned r = v.u + 0x7FFFu + ((v.u >> 16) & 1u);
  return (unsigned short)(r >> 16);
}

// ---- fused: row norms (fp32-exact) + bf16 conversion of Q,K ----
__global__ __launch_bounds__(256) void kNC(const float* __restrict__ Q,
                                           const float* __restrict__ K,
                                           unsigned short* __restrict__ Qb,
                                           unsigned short* __restrict__ Kb,
                                           float* __restrict__ qn,
                                           float* __restrict__ kn) {
  int tid = threadIdx.x;
  int row = blockIdx.x * 16 + (tid >> 4);  // 0..32767
  int part = tid & 15;
  const float* src; unsigned short* dst; float* nd; int r;
  if (row < BB * LL) { src = Q; dst = Qb; nd = qn; r = row; }
  else { src = K; dst = Kb; nd = kn; r = row - BB * LL; }
  const float* p = src + (size_t)r * DD + part * 8;
  f32x4 a = *(const f32x4*)p, b = *(const f32x4*)(p + 4);
  float s = a.x * a.x + a.y * a.y + a.z * a.z + a.w * a.w +
            b.x * b.x + b.y * b.y + b.z * b.z + b.w * b.w;
  s += __shfl_xor(s, 1); s += __shfl_xor(s, 2);
  s += __shfl_xor(s, 4); s += __shfl_xor(s, 8);
  u16x8 h;
  h[0] = f2bf(a.x); h[1] = f2bf(a.y); h[2] = f2bf(a.z); h[3] = f2bf(a.w);
  h[4] = f2bf(b.x); h[5] = f2bf(b.y); h[6] = f2bf(b.z); h[7] = f2bf(b.w);
  *(u16x8*)(dst + (size_t)r * DD + part * 8) = h;
  if (part == 0) nd[r] = s;
}

// ---- V transpose to bf16: VT[b][d][k] = bf16(V[b][k][d]) ----
__global__ __launch_bounds__(256) void kVT(const float* __restrict__ V,
                                           unsigned short* __restrict__ VT) {
  __shared__ unsigned short t[128][68];
  int bx = blockIdx.x;
  int kt = bx & 63, b = bx >> 6;
  int k0 = kt * 64;
  int tid = threadIdx.x;
  const float* Vb = V + ((size_t)b * LL + k0) * DD;
  #pragma unroll
  for (int i = 0; i < 8; ++i) {
    int flat = tid + i * 256;
    int row = flat >> 5, c4 = flat & 31;
    f32x4 v = *(const f32x4*)(Vb + row * DD + c4 * 4);
    #pragma unroll
    for (int j = 0; j < 4; ++j) t[c4 * 4 + j][row] = f2bf(v[j]);
  }
  __syncthreads();
  unsigned short* Ob = VT + (size_t)b * DD * LL + k0;
  #pragma unroll
  for (int i = 0; i < 8; ++i) {
    int flat = tid + i * 256;
    int d = flat >> 4, c = flat & 15;
    *(u16x4*)(Ob + (size_t)d * LL + c * 4) = *(const u16x4*)&t[d][c * 4];
  }
}

// ---- kernel A12: kA4 + kB5-style load/consume split ----
// grid 1024: qb(64) x b(4) x ks(4), (256,2). Wave w owns q rows
// [qb*64+w*16,+16) over k in [ks*1024,+1024). Per tile:
//   KLOAD(t+1): 16 raw K-frag loads -> regs (no consumer attached)
//   STORE(t):   ds_read (swizzled) + exp + 4rows x 256B stores  [covers latency]
//   MFMA(t+1):  consume K-frags -> S regs
//   SPILL(t+1): ds_write S into alternate buffer
// Mask 2-buffer prefetch; l_acc lane-local, reduced once at end.
__global__ __launch_bounds__(256, 2) void kA12(
    const unsigned short* __restrict__ Qb, const unsigned short* __restrict__ Kb,
    const int* __restrict__ mask, const float* __restrict__ qn,
    const float* __restrict__ kn, float* __restrict__ scores,
    float* __restrict__ dist2, float* __restrict__ l_part) {
  __shared__ float slds[2][4][16][64];  // [buf][wave][q][k-chunk], XOR-swizzled
  int bx = blockIdx.x;
  int qb = bx & 63, b = (bx >> 6) & 3, ks = bx >> 8;
  int tid = threadIdx.x;
  int w = tid >> 6, lane = tid & 63, lr = lane >> 4, lc = lane & 15;
  int qg = qb * 64 + w * 16;
  size_t bL = (size_t)b * LL;

  bf16x8 qf[4];
  {
    const unsigned short* qp = Qb + (bL + qg + lc) * DD;
    #pragma unroll
    for (int c = 0; c < 4; ++c)
      qf[c] = *(const bf16x8*)(qp + c * 32 + lr * 8);
  }

  float qn_s[4];
  size_t rowoff[4];
  #pragma unroll
  for (int s = 0; s < 4; ++s) {
    qn_s[s] = qn[bL + qg + s * 4 + lr];
    rowoff[s] = (bL + qg + s * 4 + lr) * (size_t)LL;
  }
  float l_acc[4] = {0.f, 0.f, 0.f, 0.f};

  bf16x8 kr[4][4];  // [m][c] K fragments for one tile (64 VGPR)

  auto KLOAD = [&](int t) {
    int tc = (t <= 15) ? t : 0;
    int k0 = ks * 1024 + tc * 64;
    #pragma unroll
    for (int m = 0; m < 4; ++m) {
      const unsigned short* kp = Kb + (bL + k0 + m * 16 + lc) * DD;
      #pragma unroll
      for (int c = 0; c < 4; ++c)
        kr[m][c] = *(const bf16x8*)(kp + c * 32 + lr * 8);
    }
  };

  auto MFMA_SPILL = [&](int buf) {
    #pragma unroll
    for (int m = 0; m < 4; ++m) {
      f32x4 S = (f32x4){0.f, 0.f, 0.f, 0.f};
      #pragma unroll
      for (int c = 0; c < 4; ++c)
        S = __builtin_amdgcn_mfma_f32_16x16x32_bf16(kr[m][c], qf[c], S, 0, 0, 0);
      int swz = ((m * 4 + lr) ^ lc) & 15;
      *(f32x4*)&slds[buf][w][lc][swz * 4] = S;
    }
  };

  auto LOADM = [&](i32x4 (&mr)[4], int t) {
    int tc = (t <= 15) ? t : 0;  // tail dup is harmless
    int k0 = ks * 1024 + tc * 64;
    #pragma unroll
    for (int s = 0; s < 4; ++s)
      mr[s] = *(const i32x4*)(mask + rowoff[s] + k0 + lc * 4);
  };

  auto STORE = [&](i32x4 (&mr)[4], int t, int buf) {
    int k0 = ks * 1024 + t * 64;
    f32x4 kn4 = *(const f32x4*)(kn + bL + k0 + lc * 4);
    #pragma unroll
    for (int s = 0; s < 4; ++s) {
      int row = s * 4 + lr;
      int swz = (lc ^ row) & 15;
      f32x4 S = *(const f32x4*)&slds[buf][w][row][swz * 4];
      f32x4 d2, sv;
      float le = 0.f;
      #pragma unroll
      for (int r = 0; r < 4; ++r) {
        float d = qn_s[s] + kn4[r] - 2.0f * S[r];
        d2[r] = d;
        float sc = d * (-1.0f / 256.0f);
        bool ms = (mr[s][r] == 0);
        sv[r] = ms ? -__builtin_inff() : sc;
        le += ms ? 0.f : __expf(sc);
      }
      size_t off = rowoff[s] + k0 + lc * 4;
      *(f32x4*)(dist2 + off) = d2;
      *(f32x4*)(scores + off) = sv;
      l_acc[s] += le;  // lane-local; reduced once at kernel end
    }
  };

  i32x4 mA[4], mB[4];
  LOADM(mA, 0);
  LOADM(mB, 1);
  KLOAD(0);
  MFMA_SPILL(0);      // tile 0 -> buf 0
  #pragma unroll
  for (int tt = 0; tt < 8; ++tt) {
    // even tile t = 2tt (in buf0): store it; pipeline tile 2tt+1 (buf1)
    KLOAD(2 * tt + 1);
    STORE(mA, 2 * tt, 0);
    LOADM(mA, 2 * tt + 2);
    MFMA_SPILL(1);
    // odd tile t = 2tt+1 (in buf1): store it; pipeline tile 2tt+2 (buf0)
    KLOAD(2 * tt + 2);
    STORE(mB, 2 * tt + 1, 1);
    LOADM(mB, 2 * tt + 3);
    if (tt < 7) MFMA_SPILL(0);
  }

  // reduce each l_acc[s] over the 16 k-segments (lane bits 0..3)
  #pragma unroll
  for (int s = 0; s < 4; ++s) {
    float v = l_acc[s];
    v += __shfl_xor(v, 1); v += __shfl_xor(v, 2);
    v += __shfl_xor(v, 4); v += __shfl_xor(v, 8);
    if (lc == 0)
      l_part[(size_t)ks * (BB * LL) + bL + qg + s * 4 + lr] = v;
  }
}

// ---- kernel B5: double-buffered, reg-prefetched, 1 barrier/iter ----
__global__ __launch_bounds__(256, 2) void kB5(
    const float* __restrict__ scores, const float* __restrict__ l_part,
    const unsigned short* __restrict__ VT, float* __restrict__ attn,
    float* __restrict__ O_part) {
  __shared__ short p_lds[2][64][72];
  __shared__ short v_lds[2][128][72];
  __shared__ float rl_lds[64];
  int bx = blockIdx.x;
  int qb = bx & 63, b = (bx >> 6) & 3, ks = bx >> 8;
  int tid = threadIdx.x;
  int wq = tid >> 6, l = tid & 63, lr = l >> 4, lc = l & 15;
  int q0 = qb * 64;
  int k_base = ks * 1024;

  if (tid < 64) {
    float s = 0.f;
    #pragma unroll
    for (int sp = 0; sp < 4; ++sp)
      s += l_part[(size_t)sp * (BB * LL) + (size_t)b * LL + q0 + tid];
    rl_lds[tid] = 1.0f / s;
  }

  const float* Sb = scores + (size_t)b * LL * LL + (size_t)q0 * LL;
  float* Ab = attn + (size_t)b * LL * LL + (size_t)q0 * LL;
  const unsigned short* Vb = VT + (size_t)b * DD * LL;

  int srow[4], sc4[4];
  #pragma unroll
  for (int i = 0; i < 4; ++i) {
    int flat = tid + i * 256;
    srow[i] = flat >> 4; sc4[i] = flat & 15;
  }
  int vd[8], vc[8];
  #pragma unroll
  for (int i = 0; i < 8; ++i) {
    int flat = tid + i * 256;
    vd[i] = flat >> 4; vc[i] = flat & 15;
  }

  f32x4 rS[4];
  u16x4 rV[8];
  auto LOADT = [&](int t) {
    int k0 = k_base + t * 64;
    #pragma unroll
    for (int i = 0; i < 4; ++i)
      rS[i] = __builtin_nontemporal_load(
          (const f32x4*)(Sb + (size_t)srow[i] * LL + k0 + sc4[i] * 4));
    #pragma unroll
    for (int i = 0; i < 8; ++i)
      rV[i] = *(const u16x4*)(Vb + (size_t)vd[i] * LL + k0 + vc[i] * 4);
  };

  auto PROCESS = [&](int t, int buf) {
    int k0 = k_base + t * 64;
    #pragma unroll
    for (int i = 0; i < 4; ++i) {
      float r = rl_lds[srow[i]];
      f32x4 s4 = rS[i];
      f32x4 p4;
      p4.x = __expf(s4.x) * r; p4.y = __expf(s4.y) * r;
      p4.z = __expf(s4.z) * r; p4.w = __expf(s4.w) * r;
      *(f32x4*)(Ab + (size_t)srow[i] * LL + k0 + sc4[i] * 4) = p4;
      u16x4 h;
      h[0] = f2bf(p4.x); h[1] = f2bf(p4.y); h[2] = f2bf(p4.z); h[3] = f2bf(p4.w);
      *(u16x4*)&p_lds[buf][srow[i]][sc4[i] * 4] = h;
    }
    #pragma unroll
    for (int i = 0; i < 8; ++i)
      *(u16x4*)&v_lds[buf][vd[i]][vc[i] * 4] = rV[i];
  };

  f32x4 o[8];
  #pragma unroll
  for (int f = 0; f < 8; ++f) o[f] = (f32x4){0.f, 0.f, 0.f, 0.f};

  LOADT(0);
  __syncthreads();          // rl_lds ready
  PROCESS(0, 0);
  LOADT(1);
  __syncthreads();          // buf0 ready

  for (int t = 0; t < 16; ++t) {
    int cur = t & 1;
    bf16x8 pa[2];
    #pragma unroll
    for (int c = 0; c < 2; ++c)
      pa[c] = *(bf16x8*)&p_lds[cur][wq * 16 + lc][c * 32 + lr * 8];
    #pragma unroll
    for (int f = 0; f < 8; ++f) {
      #pragma unroll
      for (int c = 0; c < 2; ++c) {
        bf16x8 vb = *(bf16x8*)&v_lds[cur][f * 16 + lc][c * 32 + lr * 8];
        o[f] = __builtin_amdgcn_mfma_f32_16x16x32_bf16(pa[c], vb, o[f], 0, 0, 0);
      }
    }
    if (t < 15) {
      PROCESS(t + 1, cur ^ 1);
      if (t < 14) LOADT(t + 2);
    }
    __syncthreads();
  }

  float* Ob = O_part + (size_t)ks * ((size_t)BB * LL * DD);
  #pragma unroll
  for (int f = 0; f < 8; ++f) {
    #pragma unroll
    for (int r = 0; r < 4; ++r) {
      int row = q0 + wq * 16 + lr * 4 + r;
      Ob[((size_t)b * LL + row) * DD + f * 16 + lc] = o[f][r];
    }
  }
}

// ---- reduce the four O partials into out ----
__global__ __launch_bounds__(256) void kR(const float* __restrict__ O_part,
                                          float* __restrict__ out) {
  size_t idx = (size_t)blockIdx.x * 256 + threadIdx.x;
  const size_t N4 = (size_t)BB * LL * DD / 4;
  const f32x4* a = (const f32x4*)O_part;
  f32x4 v = (a[idx] + a[idx + N4]) + (a[idx + 2 * N4] + a[idx + 3 * N4]);
  ((f32x4*)out)[idx] = v;
}

extern "C" void kernel_launch(void* const* d_in, const int* in_sizes, int n_in,
                              void* d_out, int out_size, void* d_ws, size_t ws_size,
                              hipStream_t stream) {
  const float* Q = (const float*)d_in[0];
  const float* K = (const float*)d_in[1];
  const float* V = (const float*)d_in[2];
  const int* mask = (const int*)d_in[3];

  float* out = (float*)d_out;                        // [4,4096,128]
  float* attn = out + (size_t)BB * LL * DD;          // [4,4096,4096]
  float* scores = attn + (size_t)BB * LL * LL;       // [4,4096,4096]
  float* dist2 = scores + (size_t)BB * LL * LL;      // [4,4096,4096]

  float* qn = (float*)d_ws;                                   // 16384 f
  float* kn = qn + BB * LL;                                   // 16384 f
  float* l_part = kn + BB * LL;                               // 4*16384 f
  unsigned short* Qbf = (unsigned short*)(l_part + 4 * BB * LL);   // 4 MB
  unsigned short* Kbf = Qbf + (size_t)BB * LL * DD;                // 4 MB
  unsigned short* VTb = Kbf + (size_t)BB * LL * DD;                // 4 MB
  float* O_part = (float*)(VTb + (size_t)BB * LL * DD);            // 4 x 8 MB

  hipLaunchKernelGGL(kNC, dim3(2048), dim3(256), 0, stream, Q, K, Qbf, Kbf, qn, kn);
  hipLaunchKernelGGL(kVT, dim3(256), dim3(256), 0, stream, V, VTb);
  hipLaunchKernelGGL(kA12, dim3(1024), dim3(256), 0, stream, Qbf, Kbf, mask, qn,
                     kn, scores, dist2, l_part);
  hipLaunchKernelGGL(kB5, dim3(1024), dim3(256), 0, stream, scores, l_part, VTb,
                     attn, O_part);
  hipLaunchKernelGGL(kR, dim3(2048), dim3(256), 0, stream, O_part, out);
}

// Round 12
// 409.975 us; speedup vs baseline: 1.4469x; 1.0424x over previous
//
#include <hip/hip_runtime.h>

#define BB 4
#define LL 4096
#define DD 128

typedef float f32x4 __attribute__((ext_vector_type(4)));
typedef short bf16x8 __attribute__((ext_vector_type(8)));
typedef unsigned short u16x8 __attribute__((ext_vector_type(8)));
typedef unsigned short u16x4 __attribute__((ext_vector_type(4)));
typedef int i32x4 __attribute__((ext_vector_type(4)));

__device__ __forceinline__ unsigned short f2bf(float f) {
  union { float f; unsigned u; } v; v.f = f;
  unsigned r = v.u + 0x7FFFu + ((v.u >> 16) & 1u);
  return (unsigned short)(r >> 16);
}

// ---- fused: row norms (fp32-exact) + bf16 conversion of Q,K ----
__global__ __launch_bounds__(256) void kNC(const float* __restrict__ Q,
                                           const float* __restrict__ K,
                                           unsigned short* __restrict__ Qb,
                                           unsigned short* __restrict__ Kb,
                                           float* __restrict__ qn,
                                           float* __restrict__ kn) {
  int tid = threadIdx.x;
  int row = blockIdx.x * 16 + (tid >> 4);  // 0..32767
  int part = tid & 15;
  const float* src; unsigned short* dst; float* nd; int r;
  if (row < BB * LL) { src = Q; dst = Qb; nd = qn; r = row; }
  else { src = K; dst = Kb; nd = kn; r = row - BB * LL; }
  const float* p = src + (size_t)r * DD + part * 8;
  f32x4 a = *(const f32x4*)p, b = *(const f32x4*)(p + 4);
  float s = a.x * a.x + a.y * a.y + a.z * a.z + a.w * a.w +
            b.x * b.x + b.y * b.y + b.z * b.z + b.w * b.w;
  s += __shfl_xor(s, 1); s += __shfl_xor(s, 2);
  s += __shfl_xor(s, 4); s += __shfl_xor(s, 8);
  u16x8 h;
  h[0] = f2bf(a.x); h[1] = f2bf(a.y); h[2] = f2bf(a.z); h[3] = f2bf(a.w);
  h[4] = f2bf(b.x); h[5] = f2bf(b.y); h[6] = f2bf(b.z); h[7] = f2bf(b.w);
  *(u16x8*)(dst + (size_t)r * DD + part * 8) = h;
  if (part == 0) nd[r] = s;
}

// ---- V transpose to bf16: VT[b][d][k] = bf16(V[b][k][d]) ----
__global__ __launch_bounds__(256) void kVT(const float* __restrict__ V,
                                           unsigned short* __restrict__ VT) {
  __shared__ unsigned short t[128][68];
  int bx = blockIdx.x;
  int kt = bx & 63, b = bx >> 6;
  int k0 = kt * 64;
  int tid = threadIdx.x;
  const float* Vb = V + ((size_t)b * LL + k0) * DD;
  #pragma unroll
  for (int i = 0; i < 8; ++i) {
    int flat = tid + i * 256;
    int row = flat >> 5, c4 = flat & 31;
    f32x4 v = *(const f32x4*)(Vb + row * DD + c4 * 4);
    #pragma unroll
    for (int j = 0; j < 4; ++j) t[c4 * 4 + j][row] = f2bf(v[j]);
  }
  __syncthreads();
  unsigned short* Ob = VT + (size_t)b * DD * LL + k0;
  #pragma unroll
  for (int i = 0; i < 8; ++i) {
    int flat = tid + i * 256;
    int d = flat >> 4, c = flat & 15;
    *(u16x4*)(Ob + (size_t)d * LL + c * 4) = *(const u16x4*)&t[d][c * 4];
  }
}

// ---- kernel A4: dist2 + scores + row-sum-exp, full-line stores ----
// grid 1024: qb(64) x b(4) x ks(4). 4 waves/block; wave w owns q rows
// [qb*64+w*16, +16) over k in [ks*1024, +1024). Swapped MFMA (A=K,B=Q)
// gives lane 4 consecutive k; S-tile transposed via XOR-swizzled LDS so
// every mask-load / dist2-store / scores-store instruction covers 256B
// contiguous per row (full 128B lines). Row sums stay in registers.
__global__ __launch_bounds__(256, 2) void kA4(
    const unsigned short* __restrict__ Qb, const unsigned short* __restrict__ Kb,
    const int* __restrict__ mask, const float* __restrict__ qn,
    const float* __restrict__ kn, float* __restrict__ scores,
    float* __restrict__ dist2, float* __restrict__ l_part) {
  __shared__ float slds[4][16][64];  // [wave][q][k-chunk], XOR-swizzled in k
  int bx = blockIdx.x;
  int qb = bx & 63, b = (bx >> 6) & 3, ks = bx >> 8;
  int tid = threadIdx.x;
  int w = tid >> 6, lane = tid & 63, lr = lane >> 4, lc = lane & 15;
  int qg = qb * 64 + w * 16;
  size_t bL = (size_t)b * LL;

  bf16x8 qf[4];
  {
    const unsigned short* qp = Qb + (bL + qg + lc) * DD;
    #pragma unroll
    for (int c = 0; c < 4; ++c)
      qf[c] = *(const bf16x8*)(qp + c * 32 + lr * 8);
  }

  float qn_s[4];
  size_t rowoff[4];
  #pragma unroll
  for (int s = 0; s < 4; ++s) {
    qn_s[s] = qn[bL + qg + s * 4 + lr];
    rowoff[s] = (bL + qg + s * 4 + lr) * (size_t)LL;
  }
  float l_acc[4] = {0.f, 0.f, 0.f, 0.f};

  auto MFMA_PHASE = [&](int t) {
    int k0 = ks * 1024 + t * 64;
    #pragma unroll
    for (int m = 0; m < 4; ++m) {
      const unsigned short* kp = Kb + (bL + k0 + m * 16 + lc) * DD;
      f32x4 S = (f32x4){0.f, 0.f, 0.f, 0.f};
      #pragma unroll
      for (int c = 0; c < 4; ++c) {
        bf16x8 af = *(const bf16x8*)(kp + c * 32 + lr * 8);
        S = __builtin_amdgcn_mfma_f32_16x16x32_bf16(af, qf[c], S, 0, 0, 0);
      }
      int swz = ((m * 4 + lr) ^ lc) & 15;
      *(f32x4*)&slds[w][lc][swz * 4] = S;
    }
  };

  auto LOADM = [&](i32x4 (&mr)[4], int t) {
    int k0 = ks * 1024 + t * 64;
    #pragma unroll
    for (int s = 0; s < 4; ++s)
      mr[s] = *(const i32x4*)(mask + rowoff[s] + k0 + lc * 4);
  };

  auto STORE_PHASE = [&](i32x4 (&mr)[4], int t) {
    int k0 = ks * 1024 + t * 64;
    f32x4 kn4 = *(const f32x4*)(kn + bL + k0 + lc * 4);
    #pragma unroll
    for (int s = 0; s < 4; ++s) {
      int row = s * 4 + lr;
      int swz = (lc ^ row) & 15;
      f32x4 S = *(const f32x4*)&slds[w][row][swz * 4];
      f32x4 d2, sv;
      float le = 0.f;
      #pragma unroll
      for (int r = 0; r < 4; ++r) {
        float d = qn_s[s] + kn4[r] - 2.0f * S[r];
        d2[r] = d;
        float sc = d * (-1.0f / 256.0f);
        bool ms = (mr[s][r] == 0);
        sv[r] = ms ? -__builtin_inff() : sc;
        le += ms ? 0.f : __expf(sc);
      }
      size_t off = rowoff[s] + k0 + lc * 4;
      *(f32x4*)(dist2 + off) = d2;
      *(f32x4*)(scores + off) = sv;
      le += __shfl_xor(le, 1); le += __shfl_xor(le, 2);
      le += __shfl_xor(le, 4); le += __shfl_xor(le, 8);
      l_acc[s] += le;
    }
  };

  i32x4 mA[4], mB[4];
  LOADM(mA, 0);
  #pragma unroll
  for (int tt = 0; tt < 8; ++tt) {
    MFMA_PHASE(2 * tt);
    LOADM(mB, 2 * tt + 1);
    STORE_PHASE(mA, 2 * tt);
    MFMA_PHASE(2 * tt + 1);
    LOADM(mA, (tt < 7) ? (2 * tt + 2) : 0);
    STORE_PHASE(mB, 2 * tt + 1);
  }

  if (lc == 0) {
    #pragma unroll
    for (int s = 0; s < 4; ++s)
      l_part[(size_t)ks * (BB * LL) + bL + qg + s * 4 + lr] = l_acc[s];
  }
}

// ---- kernel B5: double-buffered, reg-prefetched, 1 barrier/iter ----
__global__ __launch_bounds__(256, 2) void kB5(
    const float* __restrict__ scores, const float* __restrict__ l_part,
    const unsigned short* __restrict__ VT, float* __restrict__ attn,
    float* __restrict__ O_part) {
  __shared__ short p_lds[2][64][72];
  __shared__ short v_lds[2][128][72];
  __shared__ float rl_lds[64];
  int bx = blockIdx.x;
  int qb = bx & 63, b = (bx >> 6) & 3, ks = bx >> 8;
  int tid = threadIdx.x;
  int wq = tid >> 6, l = tid & 63, lr = l >> 4, lc = l & 15;
  int q0 = qb * 64;
  int k_base = ks * 1024;

  if (tid < 64) {
    float s = 0.f;
    #pragma unroll
    for (int sp = 0; sp < 4; ++sp)
      s += l_part[(size_t)sp * (BB * LL) + (size_t)b * LL + q0 + tid];
    rl_lds[tid] = 1.0f / s;
  }

  const float* Sb = scores + (size_t)b * LL * LL + (size_t)q0 * LL;
  float* Ab = attn + (size_t)b * LL * LL + (size_t)q0 * LL;
  const unsigned short* Vb = VT + (size_t)b * DD * LL;

  int srow[4], sc4[4];
  #pragma unroll
  for (int i = 0; i < 4; ++i) {
    int flat = tid + i * 256;
    srow[i] = flat >> 4; sc4[i] = flat & 15;
  }
  int vd[8], vc[8];
  #pragma unroll
  for (int i = 0; i < 8; ++i) {
    int flat = tid + i * 256;
    vd[i] = flat >> 4; vc[i] = flat & 15;
  }

  f32x4 rS[4];
  u16x4 rV[8];
  auto LOADT = [&](int t) {
    int k0 = k_base + t * 64;
    #pragma unroll
    for (int i = 0; i < 4; ++i)
      rS[i] = __builtin_nontemporal_load(
          (const f32x4*)(Sb + (size_t)srow[i] * LL + k0 + sc4[i] * 4));
    #pragma unroll
    for (int i = 0; i < 8; ++i)
      rV[i] = *(const u16x4*)(Vb + (size_t)vd[i] * LL + k0 + vc[i] * 4);
  };

  auto PROCESS = [&](int t, int buf) {
    int k0 = k_base + t * 64;
    #pragma unroll
    for (int i = 0; i < 4; ++i) {
      float r = rl_lds[srow[i]];
      f32x4 s4 = rS[i];
      f32x4 p4;
      p4.x = __expf(s4.x) * r; p4.y = __expf(s4.y) * r;
      p4.z = __expf(s4.z) * r; p4.w = __expf(s4.w) * r;
      *(f32x4*)(Ab + (size_t)srow[i] * LL + k0 + sc4[i] * 4) = p4;
      u16x4 h;
      h[0] = f2bf(p4.x); h[1] = f2bf(p4.y); h[2] = f2bf(p4.z); h[3] = f2bf(p4.w);
      *(u16x4*)&p_lds[buf][srow[i]][sc4[i] * 4] = h;
    }
    #pragma unroll
    for (int i = 0; i < 8; ++i)
      *(u16x4*)&v_lds[buf][vd[i]][vc[i] * 4] = rV[i];
  };

  f32x4 o[8];
  #pragma unroll
  for (int f = 0; f < 8; ++f) o[f] = (f32x4){0.f, 0.f, 0.f, 0.f};

  LOADT(0);
  __syncthreads();          // rl_lds ready
  PROCESS(0, 0);
  LOADT(1);
  __syncthreads();          // buf0 ready

  for (int t = 0; t < 16; ++t) {
    int cur = t & 1;
    bf16x8 pa[2];
    #pragma unroll
    for (int c = 0; c < 2; ++c)
      pa[c] = *(bf16x8*)&p_lds[cur][wq * 16 + lc][c * 32 + lr * 8];
    #pragma unroll
    for (int f = 0; f < 8; ++f) {
      #pragma unroll
      for (int c = 0; c < 2; ++c) {
        bf16x8 vb = *(bf16x8*)&v_lds[cur][f * 16 + lc][c * 32 + lr * 8];
        o[f] = __builtin_amdgcn_mfma_f32_16x16x32_bf16(pa[c], vb, o[f], 0, 0, 0);
      }
    }
    if (t < 15) {
      PROCESS(t + 1, cur ^ 1);
      if (t < 14) LOADT(t + 2);
    }
    __syncthreads();
  }

  float* Ob = O_part + (size_t)ks * ((size_t)BB * LL * DD);
  #pragma unroll
  for (int f = 0; f < 8; ++f) {
    #pragma unroll
    for (int r = 0; r < 4; ++r) {
      int row = q0 + wq * 16 + lr * 4 + r;
      Ob[((size_t)b * LL + row) * DD + f * 16 + lc] = o[f][r];
    }
  }
}

// ---- reduce the four O partials into out ----
__global__ __launch_bounds__(256) void kR(const float* __restrict__ O_part,
                                          float* __restrict__ out) {
  size_t idx = (size_t)blockIdx.x * 256 + threadIdx.x;
  const size_t N4 = (size_t)BB * LL * DD / 4;
  const f32x4* a = (const f32x4*)O_part;
  f32x4 v = (a[idx] + a[idx + N4]) + (a[idx + 2 * N4] + a[idx + 3 * N4]);
  ((f32x4*)out)[idx] = v;
}

extern "C" void kernel_launch(void* const* d_in, const int* in_sizes, int n_in,
                              void* d_out, int out_size, void* d_ws, size_t ws_size,
                              hipStream_t stream) {
  const float* Q = (const float*)d_in[0];
  const float* K = (const float*)d_in[1];
  const float* V = (const float*)d_in[2];
  const int* mask = (const int*)d_in[3];

  float* out = (float*)d_out;                        // [4,4096,128]
  float* attn = out + (size_t)BB * LL * DD;          // [4,4096,4096]
  float* scores = attn + (size_t)BB * LL * LL;       // [4,4096,4096]
  float* dist2 = scores + (size_t)BB * LL * LL;      // [4,4096,4096]

  float* qn = (float*)d_ws;                                   // 16384 f
  float* kn = qn + BB * LL;                                   // 16384 f
  float* l_part = kn + BB * LL;                               // 4*16384 f
  unsigned short* Qbf = (unsigned short*)(l_part + 4 * BB * LL);   // 4 MB
  unsigned short* Kbf = Qbf + (size_t)BB * LL * DD;                // 4 MB
  unsigned short* VTb = Kbf + (size_t)BB * LL * DD;                // 4 MB
  float* O_part = (float*)(VTb + (size_t)BB * LL * DD);            // 4 x 8 MB

  hipLaunchKernelGGL(kNC, dim3(2048), dim3(256), 0, stream, Q, K, Qbf, Kbf, qn, kn);
  hipLaunchKernelGGL(kVT, dim3(256), dim3(256), 0, stream, V, VTb);
  hipLaunchKernelGGL(kA4, dim3(1024), dim3(256), 0, stream, Qbf, Kbf, mask, qn,
                     kn, scores, dist2, l_part);
  hipLaunchKernelGGL(kB5, dim3(1024), dim3(256), 0, stream, scores, l_part, VTb,
                     attn, O_part);
  hipLaunchKernelGGL(kR, dim3(2048), dim3(256), 0, stream, O_part, out);
}